// Round 5
// baseline (233.411 us; speedup 1.0000x reference)
//
#include <hip/hip_runtime.h>
#include <hip/hip_bf16.h>
#include <stdint.h>

#define T_SEQ 2048
#define EMB   512
#define NH    8
#define HEAD_ALL 4096   // NH*EMB

typedef __attribute__((ext_vector_type(8)))  short short8;
typedef __attribute__((ext_vector_type(4)))  float f32x4;
typedef __attribute__((ext_vector_type(16))) float f32x16;

__device__ __forceinline__ unsigned short f2b(float f) {
    __hip_bfloat16 h = __float2bfloat16(f);
    return *reinterpret_cast<unsigned short*>(&h);
}
__device__ __forceinline__ void gload_lds16(const void* g, void* l) {
    __builtin_amdgcn_global_load_lds((__attribute__((address_space(1))) void*)(void*)(g),
                                     (__attribute__((address_space(3))) void*)(l), 16, 0, 0);
}
__device__ __forceinline__ void wg_barrier() {
    asm volatile("" ::: "memory");
    __builtin_amdgcn_s_barrier();
    asm volatile("" ::: "memory");
}
// sum of 8 bf16 packed in a short8 (exact f32 adds of bf16 values)
__device__ __forceinline__ float sum8bf16(short8 v) {
    uint4 u; __builtin_memcpy(&u, &v, 16);
    float s = __uint_as_float(u.x << 16) + __uint_as_float(u.x & 0xffff0000u);
    s += __uint_as_float(u.y << 16) + __uint_as_float(u.y & 0xffff0000u);
    s += __uint_as_float(u.z << 16) + __uint_as_float(u.z & 0xffff0000u);
    s += __uint_as_float(u.w << 16) + __uint_as_float(u.w & 0xffff0000u);
    return s;
}

// ---------------- f32 -> bf16 convert, two tensors in one launch ----------------
__global__ void cvt_bf16_2(const float* __restrict__ a, const float* __restrict__ b,
                           unsigned short* __restrict__ oa, unsigned short* __restrict__ ob, int n8) {
    const float* in = blockIdx.y ? b : a;
    unsigned short* out = blockIdx.y ? ob : oa;
    int i = blockIdx.x * 256 + threadIdx.x;
    if (i >= n8) return;
    const f32x4* p = (const f32x4*)in + 2 * (size_t)i;
    f32x4 va = p[0], vb = p[1];
    uint4 o;
    o.x = (unsigned)f2b(va[0]) | ((unsigned)f2b(va[1]) << 16);
    o.y = (unsigned)f2b(va[2]) | ((unsigned)f2b(va[3]) << 16);
    o.z = (unsigned)f2b(vb[0]) | ((unsigned)f2b(vb[1]) << 16);
    o.w = (unsigned)f2b(vb[2]) | ((unsigned)f2b(vb[3]) << 16);
    *((uint4*)out + i) = o;
}

// ------- f32 [R][C] -> bf16 [C][R] transpose-convert, z selects source -------
__global__ void transpose_cvt3_f32(const float* __restrict__ w0, const float* __restrict__ w1,
                                   const float* __restrict__ w2, unsigned short* __restrict__ out,
                                   int R, int C, long outS) {
    __shared__ unsigned short t[64][66];
    const int z = blockIdx.z;
    const float* in = (z == 0) ? w0 : ((z == 1) ? w1 : w2);
    unsigned short* ob = out + (long)z * outS;
    const int tid = threadIdx.x;
    const int r0 = blockIdx.y * 64, c0 = blockIdx.x * 64;
#pragma unroll
    for (int it = 0; it < 4; ++it) {
        int flat = it * 256 + tid;
        int r = flat >> 4, c4 = flat & 15;
        f32x4 v = *(const f32x4*)(in + (long)(r0 + r) * C + c0 + c4 * 4);
#pragma unroll
        for (int w = 0; w < 4; ++w) t[r][c4 * 4 + w] = f2b(v[w]);
    }
    __syncthreads();
#pragma unroll
    for (int it = 0; it < 2; ++it) {
        int flat = it * 256 + tid;
        int rr = flat >> 3, c8 = flat & 7;
        unsigned u[4];
#pragma unroll
        for (int w = 0; w < 4; ++w) {
            unsigned short a = t[c8 * 8 + 2 * w][rr];
            unsigned short b = t[c8 * 8 + 2 * w + 1][rr];
            u[w] = (unsigned)a | ((unsigned)b << 16);
        }
        *(uint4*)(ob + (long)(c0 + rr) * R + r0 + c8 * 8) = make_uint4(u[0], u[1], u[2], u[3]);
    }
}

// ============== 8-phase double-buffered GEMM: C = op(alpha * A @ B'^T) ==============
// 32x32x16 bf16 MFMA. A: M x kfull row-major; B': N x kfull row-major (B^T).
// BMxBN tile, BK=64, 512 threads = 8 waves (2M x 4N); wave tile (BM/2)x(BN/4).
// MB32 = M-blocks(32) per wave, NB32 = N-blocks per wave; 4 k-steps of K=16 per K-tile.
// Phase q handles (mblk,ks) pairs idx = q*MB32 .. +MB32-1 (idx = mblk*4+ks).
// A/B frag: row|col = lane&31, k = (lane>>5)*8 + e. C/D: col=lane&31,
// row = (reg&3)+8*(reg>>2)+4*(lane>>5)  [m74/m101 verified mapping].
// T2: linear LDS dest for global_load_lds; inverse-XOR-swizzled GLOBAL source
// (byte ^ ((row&7)<<4)) + same XOR on ds_read. T1: XCD chunk swizzle (nwg%8==0).
// Pipeline: A_{t+1} staged q0(/q1), B_{t+2} q2(/q3); vmcnt(LB) counted at q3.
// MODE 1: projections: batch0=K(x), 1=Q(y), 2=V(x, stored TRANSPOSED per head)
// MODE 2: S~ = exp(alpha*acc) bf16 (no-max softmax; row sums taken by MODE 4)
// MODE 3: f32 split-K partial over K-slice batch
// MODE 4: PV: accumulates row-sums of A (=S~) from fragments; out bf16 * (1/rowsum)
template<int R_>
__device__ __forceinline__ void stage2(const unsigned short* __restrict__ src, int kfull,
                                       short* ldsbase, int i, int tid, int wid) {
#pragma unroll
    for (int s = 0; s < 2; ++s) {
        const int ii = i + s;
        const int r = ii * 64 + (tid >> 3);
        const int d = (tid & 7) * 16;                  // dest byte within 128B row
        const int sc = (d ^ ((r & 7) << 4)) >> 1;      // inverse-swizzled src col (elems)
        gload_lds16(src + (long)r * kfull + sc, ldsbase + ii * 4096 + wid * 512);
    }
}

template<int BM, int BN, int KTILES, int MODE, int MINW = 2>
__global__ __launch_bounds__(512, MINW)
void gemm8p(const unsigned short* __restrict__ A, const unsigned short* __restrict__ A2,
            const unsigned short* __restrict__ B, void* __restrict__ Cout,
            int kfull, float alpha, long As, long Bs, long Cs, int ldc)
{
    static_assert(KTILES >= 3, "pipeline needs >=3 K-tiles");
    constexpr int ATILE = BM * 64;
    constexpr int BTILE = BN * 64;
    constexpr int LA = BM / 64;           // gloads per A K-tile
    constexpr int LB = BN / 64;
    constexpr int MB32 = (BM / 2) / 32;   // 32-row blocks per wave
    constexpr int NB32 = (BN / 4) / 32;   // 32-col blocks per wave

    __shared__ __align__(16) short lds[2 * (ATILE + BTILE)];
    __shared__ float rbuf[8][(MODE == 4) ? MB32 : 1][32];   // MODE 4 rinv broadcast

    const int tid = threadIdx.x;
    const int wid = tid >> 6, lane = tid & 63;
    const int wm = wid >> 2, wn = wid & 3;
    const int l31 = lane & 31, hi = lane >> 5;

    // ---- T1: XCD chunk swizzle ----
    const int nwg = gridDim.x * gridDim.y * gridDim.z;
    int flat = blockIdx.x + gridDim.x * (blockIdx.y + gridDim.y * blockIdx.z);
    flat = (flat & 7) * (nwg >> 3) + (flat >> 3);
    const int bx = flat % gridDim.x;
    const int rem = flat / gridDim.x;
    const int by = rem % gridDim.y;
    const long batch = rem / gridDim.y;

    const int bm = by * BM, bn = bx * BN;

    const unsigned short* Ab;
    const unsigned short* Bb;
    int koff = 0;
    if constexpr (MODE == 1) { Ab = (batch == 1) ? A2 : A; Bb = B + batch * Bs; }
    else if constexpr (MODE == 3) { Ab = A; Bb = B; koff = (int)batch * (KTILES * 64); }
    else { Ab = A + batch * As; Bb = B + batch * Bs; }

    const unsigned short* Ag = Ab + (long)bm * kfull + koff;
    const unsigned short* Bg = Bb + (long)bn * kfull + koff;

    f32x16 acc[MB32][NB32];
#pragma unroll
    for (int i = 0; i < MB32; i++)
#pragma unroll
        for (int j = 0; j < NB32; j++) acc[i][j] = 0.f;

    float rowacc[MB32];
#pragma unroll
    for (int i = 0; i < MB32; i++) rowacc[i] = 0.f;

    // ---- prologue: stage A_0, B_0, B_1 ----
#pragma unroll
    for (int i = 0; i < LA; i += 2) stage2<BM>(Ag, kfull, lds, i, tid, wid);
#pragma unroll
    for (int i = 0; i < LB; i += 2) stage2<BN>(Bg, kfull, lds + 2 * ATILE, i, tid, wid);
#pragma unroll
    for (int i = 0; i < LB; i += 2) stage2<BN>(Bg + 64, kfull, lds + 2 * ATILE + BTILE, i, tid, wid);
    if constexpr (LB == 4) asm volatile("s_waitcnt vmcnt(4)" ::: "memory");
    else                   asm volatile("s_waitcnt vmcnt(2)" ::: "memory");
    wg_barrier();

    // ---- main loop ----
#pragma unroll 2
    for (int t = 0; t < KTILES; ++t) {
        short* la  = lds + (t & 1) * ATILE;
        short* laN = lds + ((t + 1) & 1) * ATILE;
        short* lb  = lds + 2 * ATILE + (t & 1) * BTILE;
        const int kA = (t + 1) * 64;
        const int kB = (t + 2) * 64;

        short8 bfrag[NB32][4];
#pragma unroll
        for (int q = 0; q < 4; ++q) {
            if (q == 0) {
#pragma unroll
                for (int nb = 0; nb < NB32; ++nb)
#pragma unroll
                    for (int ks = 0; ks < 4; ++ks) {
                        const int r = wn * (BN / 4) + nb * 32 + l31;
                        const int cb = ks * 32 + hi * 16;
                        bfrag[nb][ks] = *(const short8*)(lb + r * 64 + ((cb ^ ((r & 7) << 4)) >> 1));
                    }
            }
            short8 afrag[MB32];
#pragma unroll
            for (int p = 0; p < MB32; ++p) {
                const int idx = q * MB32 + p;
                const int mblk = idx >> 2, ks = idx & 3;
                const int r = wm * (BM / 2) + mblk * 32 + l31;
                const int cb = ks * 32 + hi * 16;
                afrag[p] = *(const short8*)(la + r * 64 + ((cb ^ ((r & 7) << 4)) >> 1));
                if constexpr (MODE == 4) rowacc[mblk] += sum8bf16(afrag[p]);
            }
            if (t + 1 < KTILES) {
                if (q == 0) stage2<BM>(Ag + kA, kfull, laN, 0, tid, wid);
                if (q == 1 && LA == 4) stage2<BM>(Ag + kA, kfull, laN, 2, tid, wid);
            }
            if (t + 2 < KTILES) {
                if (q == 2) stage2<BN>(Bg + kB, kfull, lb, 0, tid, wid);
                if (q == 3 && LB == 4) stage2<BN>(Bg + kB, kfull, lb, 2, tid, wid);
            }
            wg_barrier();
            __builtin_amdgcn_s_setprio(1);
#pragma unroll
            for (int p = 0; p < MB32; ++p) {
                const int idx = q * MB32 + p;
                const int mblk = idx >> 2, ks = idx & 3;
#pragma unroll
                for (int nb = 0; nb < NB32; ++nb)
                    acc[mblk][nb] = __builtin_amdgcn_mfma_f32_32x32x16_bf16(
                        afrag[p], bfrag[nb][ks], acc[mblk][nb], 0, 0, 0);
            }
            __builtin_amdgcn_s_setprio(0);
            if (q == 3) {
                if (t + 2 < KTILES) {
                    if constexpr (LB == 4) asm volatile("s_waitcnt vmcnt(4)" ::: "memory");
                    else                   asm volatile("s_waitcnt vmcnt(2)" ::: "memory");
                } else {
                    asm volatile("s_waitcnt vmcnt(0)" ::: "memory");
                }
            }
            wg_barrier();
        }
    }

    // ---- MODE 4: finish row sums (one cross-half shfl) and broadcast 1/sum ----
    if constexpr (MODE == 4) {
#pragma unroll
        for (int mb = 0; mb < MB32; ++mb) {
            float rs = rowacc[mb] + __shfl_xor(rowacc[mb], 32);
            if (lane < 32) rbuf[wid][mb][l31] = 1.0f / rs;
        }
    }

    // ---- epilogue ----
#pragma unroll
    for (int mb = 0; mb < MB32; ++mb)
#pragma unroll
        for (int reg = 0; reg < 16; ++reg) {
            const int rloc = (reg & 3) + 8 * (reg >> 2) + 4 * hi;
            const int row = bm + wm * (BM / 2) + mb * 32 + rloc;
#pragma unroll
            for (int nb = 0; nb < NB32; ++nb) {
                const int col = bn + wn * (BN / 4) + nb * 32 + l31;
                const float v = acc[mb][nb][reg] * alpha;
                if constexpr (MODE == 1) {
                    unsigned short* C = (unsigned short*)Cout + batch * Cs;
                    if (batch == 2)   // V: store transposed per head
                        C[(long)(col >> 9) * ((long)T_SEQ * EMB) + (long)(col & 511) * T_SEQ + row] = f2b(v);
                    else              // K, Q: head-split row-major
                        C[(long)(col >> 9) * ((long)T_SEQ * EMB) + (long)row * EMB + (col & 511)] = f2b(v);
                } else if constexpr (MODE == 2) {
                    unsigned short* C = (unsigned short*)Cout + batch * Cs;
                    C[(long)row * ldc + col] = f2b(__expf(v));
                } else if constexpr (MODE == 3) {
                    float* C = (float*)Cout + batch * ((long)T_SEQ * EMB);
                    C[(long)row * ldc + col] = v;
                } else { // MODE 4
                    unsigned short* C = (unsigned short*)Cout + batch * Cs;
                    C[(long)row * ldc + col] = f2b(v * rbuf[wid][mb][rloc]);
                }
            }
        }
}

// ---------------- split-K reduce + bias: out = sum_s part[s] + bias ----------------
__global__ void reduce_bias(const float* __restrict__ part, const float* __restrict__ bias,
                            float* __restrict__ out) {
    const int i = blockIdx.x * 256 + threadIdx.x;   // float4 index; total T*E/4
    const long stride4 = (long)T_SEQ * EMB / 4;
    const f32x4* p = (const f32x4*)part;
    f32x4 s = p[i];
#pragma unroll
    for (int sl = 1; sl < 4; ++sl) s += p[i + sl * stride4];
    f32x4 b = *(const f32x4*)(bias + ((i * 4) % EMB));
    *((f32x4*)out + i) = s + b;
}

extern "C" void kernel_launch(void* const* d_in, const int* in_sizes, int n_in,
                              void* d_out, int out_size, void* d_ws, size_t ws_size,
                              hipStream_t stream)
{
    const float* x  = (const float*)d_in[0];
    const float* y  = (const float*)d_in[1];
    const float* Wk = (const float*)d_in[2];
    const float* Wq = (const float*)d_in[3];
    const float* Wv = (const float*)d_in[4];
    const float* Wu = (const float*)d_in[5];
    const float* bu = (const float*)d_in[6];
    char* ws = (char*)d_ws;
    const size_t MB = 1024ull * 1024ull;

    // Workspace layout, 132 MB total.
    // [0,64MB) = S~ union. Transients inside it (dead before S~ is written):
    // xb@0(2), yb@2(2), WT3@4(12). Split-K partials (16MB f32) also live at @0
    // -- written after PV consumed S~.
    unsigned short* Sb   = (unsigned short*)(ws + 0);        // 64 MB [union]
    unsigned short* xb   = (unsigned short*)(ws + 0);        // 2 MB  [transient]
    unsigned short* yb   = (unsigned short*)(ws + 2 * MB);   // 2 MB  [transient]
    unsigned short* WT3  = (unsigned short*)(ws + 4 * MB);   // 12 MB: WkT,WqT,WvT [transient]
    unsigned short* Kb   = (unsigned short*)(ws + 64 * MB);  // 16 MB
    unsigned short* Qb   = (unsigned short*)(ws + 80 * MB);  // 16 MB
    unsigned short* VTb  = (unsigned short*)(ws + 96 * MB);  // 16 MB (written by proj, batch 2)
    unsigned short* WuT  = (unsigned short*)(ws + 112 * MB); // 4 MB
    unsigned short* Ob   = (unsigned short*)(ws + 116 * MB); // 16 MB -> 132 MB total
    float*          part = (float*)(ws + 0);                 // 16 MB f32 [union w/ Sb]

    const float scale2 = 0.04419417382415922f;  // 512^-0.5 == (e^-0.25)^2
    const long TE = (long)T_SEQ * EMB;          // 1048576

    // 1) converts (x,y in one launch; Wk,Wq,Wv transposes in one z=3 launch)
    cvt_bf16_2<<<dim3(512, 2), dim3(256), 0, stream>>>(x, y, xb, yb, T_SEQ * EMB / 8);
    transpose_cvt3_f32<<<dim3(HEAD_ALL / 64, EMB / 64, 3), dim3(256), 0, stream>>>(
        Wk, Wq, Wv, WT3, EMB, HEAD_ALL, (long)2 * MB);
    transpose_cvt3_f32<<<dim3(EMB / 64, HEAD_ALL / 64, 1), dim3(256), 0, stream>>>(
        Wu, nullptr, nullptr, WuT, HEAD_ALL, EMB, 0);

    // 2) fused projections (batch0=K(x), 1=Q(y), 2=V(x) stored transposed)
    gemm8p<256, 256, 8, 1><<<dim3(HEAD_ALL / 256, T_SEQ / 256, 3), 512, 0, stream>>>(
        xb, yb, WT3, Kb, EMB, 1.f, 0, (long)2 * MB, (long)8 * MB, 0);

    // 3) S~ = exp((Q @ K^T) * e^-0.5), batched over heads
    gemm8p<256, 256, 8, 2><<<dim3(T_SEQ / 256, T_SEQ / 256, NH), 512, 0, stream>>>(
        Qb, nullptr, Kb, Sb, EMB, scale2, TE, TE, (long)T_SEQ * T_SEQ, T_SEQ);

    // 4) O = (S~ @ V) / rowsum(S~), batched; head h cols at [t][4096] offset h*512
    gemm8p<128, 256, 32, 4><<<dim3(EMB / 256, T_SEQ / 128, NH), 512, 0, stream>>>(
        Sb, nullptr, VTb, Ob, T_SEQ, 1.f, (long)T_SEQ * T_SEQ, TE, (long)EMB, HEAD_ALL);

    // 5) split-K=4 final GEMM: part[s] = O @ Wu over K-slice s (K=1024 each)
    gemm8p<128, 128, 16, 3, 4><<<dim3(EMB / 128, T_SEQ / 128, 4), 512, 0, stream>>>(
        Ob, nullptr, WuT, part, HEAD_ALL, 1.f, 0, 0, 0, EMB);

    // 6) out = sum(part) + bias, f32
    reduce_bias<<<dim3(T_SEQ * EMB / 4 / 256), dim3(256), 0, stream>>>(part, bu, (float*)d_out);
}